// Round 5
// baseline (9427.027 us; speedup 1.0000x reference)
//
#include <hip/hip_runtime.h>

typedef _Float16 h2 __attribute__((ext_vector_type(2)));
typedef _Float16 h8 __attribute__((ext_vector_type(8)));
typedef float f4 __attribute__((ext_vector_type(4)));

// ---------------- convert fp32 -> f16 ----------------
__global__ void cvt_f32_f16(const float* __restrict__ s, _Float16* __restrict__ d, int n) {
    int i = blockIdx.x * blockDim.x + threadIdx.x;
    if (i < n) d[i] = (_Float16)s[i];
}

// ---------------- x_proj GEMM: C[M][768] = A[M][256] * Bt[768][256]^T + bias ----------------
template<bool AF16>
__global__ __launch_bounds__(256, 2) void gemm_xproj(
    const void* __restrict__ Ap, const _Float16* __restrict__ Bt,
    const float* __restrict__ bias, float* __restrict__ C)
{
    __shared__ __align__(16) _Float16 As[128 * 40];
    __shared__ __align__(16) _Float16 Bs[128 * 40];
    const int tid = threadIdx.x;
    const size_t m0 = (size_t)blockIdx.x * 128;
    const int n0 = blockIdx.y * 128;
    const int lane = tid & 63, wave = tid >> 6;
    const int wm = wave >> 1, wn = wave & 1;
    const int r16 = lane & 15, kg = lane >> 4;
    f4 acc[4][4] = {};
    for (int k0 = 0; k0 < 256; k0 += 32) {
        if (k0) __syncthreads();
        #pragma unroll
        for (int u = 0; u < 2; ++u) {
            int c = tid + u * 256;
            int row = c >> 2, off = (c & 3) * 8;
            h8 av;
            if constexpr (AF16) {
                av = *(const h8*)((const _Float16*)Ap + (m0 + row) * 256 + k0 + off);
            } else {
                const float* ap = (const float*)Ap + (m0 + row) * 256 + k0 + off;
                f4 f0 = *(const f4*)ap, f1 = *(const f4*)(ap + 4);
                av[0]=(_Float16)f0[0]; av[1]=(_Float16)f0[1]; av[2]=(_Float16)f0[2]; av[3]=(_Float16)f0[3];
                av[4]=(_Float16)f1[0]; av[5]=(_Float16)f1[1]; av[6]=(_Float16)f1[2]; av[7]=(_Float16)f1[3];
            }
            *(h8*)&As[row * 40 + off] = av;
            h8 bv = *(const h8*)(Bt + (size_t)(n0 + row) * 256 + k0 + off);
            *(h8*)&Bs[row * 40 + off] = bv;
        }
        __syncthreads();
        h8 af[4], bf[4];
        #pragma unroll
        for (int mi = 0; mi < 4; ++mi) af[mi] = *(const h8*)&As[(wm*64 + mi*16 + r16) * 40 + kg * 8];
        #pragma unroll
        for (int ni = 0; ni < 4; ++ni) bf[ni] = *(const h8*)&Bs[(wn*64 + ni*16 + r16) * 40 + kg * 8];
        #pragma unroll
        for (int mi = 0; mi < 4; ++mi)
            #pragma unroll
            for (int ni = 0; ni < 4; ++ni)
                acc[mi][ni] = __builtin_amdgcn_mfma_f32_16x16x32_f16(af[mi], bf[ni], acc[mi][ni], 0, 0, 0);
    }
    #pragma unroll
    for (int mi = 0; mi < 4; ++mi)
        #pragma unroll
        for (int ni = 0; ni < 4; ++ni) {
            int col = n0 + wn*64 + ni*16 + r16;
            float bv = bias[col];
            #pragma unroll
            for (int r = 0; r < 4; ++r) {
                int row = wm*64 + mi*16 + kg*4 + r;
                C[(m0 + row) * 768 + col] = acc[mi][ni][r] + bv;
            }
        }
}

// ---------------- recurrent scan: 1024 thr, 96 weight-VGPRs/thread (fits 128 budget) ----------------
template<bool OUTF32>
__global__ __launch_bounds__(1024) void gru_scan(
    const float* __restrict__ xp,        // [B][T][768] fp32 (x_proj incl. b_ih)
    const _Float16* __restrict__ Whh,    // [768][256] f16
    const float* __restrict__ bhh,       // [768]
    float* __restrict__ o32,             // layer 2 -> d_out
    _Float16* __restrict__ o16)          // layer 1 -> next GEMM input (f16)
{
    // h stored in 4 padded k-quarter segments: stride 72 f16 = 144 B -> segment bases
    // hit banks {0,4,8,12}: the 4 distinct addresses per ds_read_b128 are conflict-free.
    __shared__ __align__(16) _Float16 hh[2][4][72];
    const int b = blockIdx.x;
    const int tid = threadIdx.x;
    const int j = tid >> 2, kq = tid & 3;          // j: output row, kq: k-quarter

    // ---- weight slice: rows {j, j+256, j+512}, k in [kq*64, kq*64+64) -> 24 int4 = 96 VGPRs ----
    int4 w4[3][8];
    {
        const _Float16* base = Whh + (size_t)j * 256 + kq * 64;
        #pragma unroll
        for (int g = 0; g < 3; ++g) {
            const int4* p = (const int4*)(base + (size_t)g * 256 * 256);
            #pragma unroll
            for (int k8 = 0; k8 < 8; ++k8) w4[g][k8] = p[k8];
        }
    }
    const float br = bhh[j], bz = bhh[j + 256], bn = bhh[j + 512];
    if (tid < 256) hh[0][tid >> 6][tid & 63] = (_Float16)1.0f;
    float hprev = 1.0f;                            // valid in kq==0 lanes
    __syncthreads();

    const float* xb = xp + (size_t)b * 2048 * 768;
    // depth-2 x_proj prefetch (kq==0 lanes only use it; keep regs minimal)
    float xr0 = 0.f, xz0 = 0.f, xn0 = 0.f, xr1 = 0.f, xz1 = 0.f, xn1 = 0.f;
    if (kq == 0) {
        xr0 = xb[j];       xz0 = xb[j + 256];       xn0 = xb[j + 512];
        xr1 = xb[768 + j]; xz1 = xb[768 + j + 256]; xn1 = xb[768 + j + 512];
    }
    int cur = 0;
    for (int t = 0; t < 2048; ++t) {
        float pr = 0.f, pz = 0.f, pn = 0.f;
        if (kq == 0) {
            const int tn = (t + 2 < 2048) ? t + 2 : 2047;
            const float* xnx = xb + (size_t)tn * 768;
            pr = xnx[j]; pz = xnx[j + 256]; pn = xnx[j + 512];
        }

        float ar = 0.f, az = 0.f, an = 0.f;
        const h8* hseg = (const h8*)&hh[cur][kq][0];
        #pragma unroll
        for (int k8 = 0; k8 < 8; ++k8) {
            h8 hc = hseg[k8];
            h2 hp[4]; __builtin_memcpy(&hp, &hc, 16);
            int4 vr = w4[0][k8], vz = w4[1][k8], vn = w4[2][k8];
            ar = __builtin_amdgcn_fdot2(__builtin_bit_cast(h2, vr.x), hp[0], ar, false);
            az = __builtin_amdgcn_fdot2(__builtin_bit_cast(h2, vz.x), hp[0], az, false);
            an = __builtin_amdgcn_fdot2(__builtin_bit_cast(h2, vn.x), hp[0], an, false);
            ar = __builtin_amdgcn_fdot2(__builtin_bit_cast(h2, vr.y), hp[1], ar, false);
            az = __builtin_amdgcn_fdot2(__builtin_bit_cast(h2, vz.y), hp[1], az, false);
            an = __builtin_amdgcn_fdot2(__builtin_bit_cast(h2, vn.y), hp[1], an, false);
            ar = __builtin_amdgcn_fdot2(__builtin_bit_cast(h2, vr.z), hp[2], ar, false);
            az = __builtin_amdgcn_fdot2(__builtin_bit_cast(h2, vz.z), hp[2], az, false);
            an = __builtin_amdgcn_fdot2(__builtin_bit_cast(h2, vn.z), hp[2], an, false);
            ar = __builtin_amdgcn_fdot2(__builtin_bit_cast(h2, vr.w), hp[3], ar, false);
            az = __builtin_amdgcn_fdot2(__builtin_bit_cast(h2, vz.w), hp[3], az, false);
            an = __builtin_amdgcn_fdot2(__builtin_bit_cast(h2, vn.w), hp[3], an, false);
        }
        // reduce over the 4 k-quarters (lanes tid&3)
        ar += __shfl_xor(ar, 1); ar += __shfl_xor(ar, 2);
        az += __shfl_xor(az, 1); az += __shfl_xor(az, 2);
        an += __shfl_xor(an, 1); an += __shfl_xor(an, 2);

        const int nxt = cur ^ 1;
        if (kq == 0) {
            float rg = 1.f / (1.f + __expf(-(xr0 + ar + br)));
            float zg = 1.f / (1.f + __expf(-(xz0 + az + bz)));
            float narg = xn0 + rg * (an + bn);
            float aa = fabsf(narg);
            float e = __expf(-2.f * aa);
            float ng = copysignf((1.f - e) / (1.f + e), narg);
            float hnew = (1.f - zg) * ng + zg * hprev;
            hprev = hnew;
            hh[nxt][j >> 6][j & 63] = (_Float16)hnew;
            size_t oi = ((size_t)b * 2048 + t) * 256 + j;
            if constexpr (OUTF32) o32[oi] = hnew; else o16[oi] = (_Float16)hnew;
            xr0 = xr1; xz0 = xz1; xn0 = xn1;
            xr1 = pr;  xz1 = pz;  xn1 = pn;
        }
        __syncthreads();
        cur = nxt;
    }
}

// ---------------- launch ----------------
extern "C" void kernel_launch(void* const* d_in, const int* in_sizes, int n_in,
                              void* d_out, int out_size, void* d_ws, size_t ws_size,
                              hipStream_t stream) {
    const float* x    = (const float*)d_in[0];
    const float* W_ih = (const float*)d_in[1];
    const float* W_hh = (const float*)d_in[2];
    const float* b_ih = (const float*)d_in[3];
    const float* b_hh = (const float*)d_in[4];
    float* out = (float*)d_out;

    char* ws = (char*)d_ws;
    float*     xproj = (float*)ws;                                   // 201,326,592 B
    _Float16*  Wih_h = (_Float16*)(ws + 201326592);
    _Float16*  Whh_h = (_Float16*)(ws + 201326592 + 786432);
    _Float16*  y1h   = (_Float16*)(ws + 201326592 + 2 * 786432);

    cvt_f32_f16<<<1536, 256, 0, stream>>>(W_ih, Wih_h, 393216);
    cvt_f32_f16<<<1536, 256, 0, stream>>>(W_hh, Whh_h, 393216);

    gemm_xproj<false><<<dim3(512, 6), 256, 0, stream>>>(x, Wih_h, b_ih, xproj);
    gru_scan<false><<<32, 1024, 0, stream>>>(xproj, Whh_h, b_hh, nullptr, y1h);

    gemm_xproj<true><<<dim3(512, 6), 256, 0, stream>>>(y1h, Wih_h + 196608, b_ih + 768, xproj);
    gru_scan<true><<<32, 1024, 0, stream>>>(xproj, Whh_h + 196608, b_hh + 768, out, nullptr);
}

// Round 6
// 6035.714 us; speedup vs baseline: 1.5619x; 1.5619x over previous
//
#include <hip/hip_runtime.h>

typedef _Float16 h2 __attribute__((ext_vector_type(2)));
typedef _Float16 h8 __attribute__((ext_vector_type(8)));
typedef float f4 __attribute__((ext_vector_type(4)));

// ---------------- convert fp32 -> f16 ----------------
__global__ void cvt_f32_f16(const float* __restrict__ s, _Float16* __restrict__ d, int n) {
    int i = blockIdx.x * blockDim.x + threadIdx.x;
    if (i < n) d[i] = (_Float16)s[i];
}

// ---------------- combined GEMM bias: b_ih + b_hh for r,z cols; b_ih for n cols ----------------
__global__ void prep_bias(const float* __restrict__ bih, const float* __restrict__ bhh,
                          float* __restrict__ b2, int n) {
    int i = blockIdx.x * blockDim.x + threadIdx.x;
    if (i < n) {
        int c = i % 768;
        float v = bih[i];
        if (c < 512) v += bhh[i];
        b2[i] = v;
    }
}

// ---------------- x_proj GEMM: C[M][768] = A[M][256] * Bt[768][256]^T + bias ----------------
template<bool AF16>
__global__ __launch_bounds__(256, 2) void gemm_xproj(
    const void* __restrict__ Ap, const _Float16* __restrict__ Bt,
    const float* __restrict__ bias, float* __restrict__ C)
{
    __shared__ __align__(16) _Float16 As[128 * 40];
    __shared__ __align__(16) _Float16 Bs[128 * 40];
    const int tid = threadIdx.x;
    const size_t m0 = (size_t)blockIdx.x * 128;
    const int n0 = blockIdx.y * 128;
    const int lane = tid & 63, wave = tid >> 6;
    const int wm = wave >> 1, wn = wave & 1;
    const int r16 = lane & 15, kg = lane >> 4;
    f4 acc[4][4] = {};
    for (int k0 = 0; k0 < 256; k0 += 32) {
        if (k0) __syncthreads();
        #pragma unroll
        for (int u = 0; u < 2; ++u) {
            int c = tid + u * 256;
            int row = c >> 2, off = (c & 3) * 8;
            h8 av;
            if constexpr (AF16) {
                av = *(const h8*)((const _Float16*)Ap + (m0 + row) * 256 + k0 + off);
            } else {
                const float* ap = (const float*)Ap + (m0 + row) * 256 + k0 + off;
                f4 f0 = *(const f4*)ap, f1 = *(const f4*)(ap + 4);
                av[0]=(_Float16)f0[0]; av[1]=(_Float16)f0[1]; av[2]=(_Float16)f0[2]; av[3]=(_Float16)f0[3];
                av[4]=(_Float16)f1[0]; av[5]=(_Float16)f1[1]; av[6]=(_Float16)f1[2]; av[7]=(_Float16)f1[3];
            }
            *(h8*)&As[row * 40 + off] = av;
            h8 bv = *(const h8*)(Bt + (size_t)(n0 + row) * 256 + k0 + off);
            *(h8*)&Bs[row * 40 + off] = bv;
        }
        __syncthreads();
        h8 af[4], bf[4];
        #pragma unroll
        for (int mi = 0; mi < 4; ++mi) af[mi] = *(const h8*)&As[(wm*64 + mi*16 + r16) * 40 + kg * 8];
        #pragma unroll
        for (int ni = 0; ni < 4; ++ni) bf[ni] = *(const h8*)&Bs[(wn*64 + ni*16 + r16) * 40 + kg * 8];
        #pragma unroll
        for (int mi = 0; mi < 4; ++mi)
            #pragma unroll
            for (int ni = 0; ni < 4; ++ni)
                acc[mi][ni] = __builtin_amdgcn_mfma_f32_16x16x32_f16(af[mi], bf[ni], acc[mi][ni], 0, 0, 0);
    }
    #pragma unroll
    for (int mi = 0; mi < 4; ++mi)
        #pragma unroll
        for (int ni = 0; ni < 4; ++ni) {
            int col = n0 + wn*64 + ni*16 + r16;
            float bv = bias[col];
            #pragma unroll
            for (int r = 0; r < 4; ++r) {
                int row = wm*64 + mi*16 + kg*4 + r;
                C[(m0 + row) * 768 + col] = acc[mi][ni][r] + bv;
            }
        }
}

// ---------------- scan body: 1024 thr, 4 thr/output, 96 weight VGPRs/thread ----------------
template<bool OUTF32>
__device__ __forceinline__ void gru_scan_body(
    const float* __restrict__ xp,        // [B][T][768] fp32 (x_proj, b_ih + b_hh(r,z) folded)
    const _Float16* __restrict__ Whh,    // [768][256] f16
    const float* __restrict__ bhh,       // [768] (only n-part used)
    float* __restrict__ o32,
    _Float16* __restrict__ o16)
{
    // 4 padded k-quarter segments, stride 72 f16 = 144 B -> bases 4 banks apart: conflict-free.
    __shared__ __align__(16) _Float16 hh[2][4][72];
    const int b = blockIdx.x;
    const int tid = threadIdx.x;
    const int j = tid >> 2, kq = tid & 3;

    // weight slice: rows {j, j+256, j+512}, k in [kq*64, kq*64+64) -> 24 int4 = 96 VGPRs
    int4 w4[3][8];
    {
        const _Float16* base = Whh + (size_t)j * 256 + kq * 64;
        #pragma unroll
        for (int g = 0; g < 3; ++g) {
            const int4* p = (const int4*)(base + (size_t)g * 256 * 256);
            #pragma unroll
            for (int k8 = 0; k8 < 8; ++k8) {
                const int4* q = p + k8;
                asm volatile("global_load_dwordx4 %0, %1, off" : "=v"(w4[g][k8]) : "v"(q));
            }
        }
        asm volatile("s_waitcnt vmcnt(0)" ::: "memory");
        __builtin_amdgcn_sched_barrier(0);
    }
    const float bn = bhh[j + 512];
    if (tid < 256) hh[0][tid >> 6][tid & 63] = (_Float16)1.0f;
    float hprev = 1.0f;
    __syncthreads();

    const float* xb = xp + (size_t)b * 2048 * 768;
    // role-split prefetch: lane kq=c (c=1,2,3) pipelines gate (c-1)'s x_proj stream
    const float* xrole = xb + (size_t)(kq ? (kq - 1) : 0) * 256 + j;
    float pipe0 = 0.f, pipe1 = 0.f;
    if (kq) { pipe0 = xrole[0]; pipe1 = xrole[768]; }
    const int lbase = (tid & 63) & ~3;   // wave-local base lane of this 4-group

    int cur = 0;
    for (int t = 0; t < 2048; ++t) {
        float pnew = 0.f;
        if (kq) {
            const int tn = (t + 2 < 2048) ? t + 2 : 2047;
            pnew = xrole[(size_t)tn * 768];
        }

        float ar = 0.f, az = 0.f, an = 0.f;
        const h8* hseg = (const h8*)&hh[cur][kq][0];
        #pragma unroll
        for (int k8 = 0; k8 < 8; ++k8) {
            h8 hc = hseg[k8];
            h2 hp[4]; __builtin_memcpy(&hp, &hc, 16);
            int4 vr = w4[0][k8], vz = w4[1][k8], vn = w4[2][k8];
            ar = __builtin_amdgcn_fdot2(__builtin_bit_cast(h2, vr.x), hp[0], ar, false);
            az = __builtin_amdgcn_fdot2(__builtin_bit_cast(h2, vz.x), hp[0], az, false);
            an = __builtin_amdgcn_fdot2(__builtin_bit_cast(h2, vn.x), hp[0], an, false);
            ar = __builtin_amdgcn_fdot2(__builtin_bit_cast(h2, vr.y), hp[1], ar, false);
            az = __builtin_amdgcn_fdot2(__builtin_bit_cast(h2, vz.y), hp[1], az, false);
            an = __builtin_amdgcn_fdot2(__builtin_bit_cast(h2, vn.y), hp[1], an, false);
            ar = __builtin_amdgcn_fdot2(__builtin_bit_cast(h2, vr.z), hp[2], ar, false);
            az = __builtin_amdgcn_fdot2(__builtin_bit_cast(h2, vz.z), hp[2], az, false);
            an = __builtin_amdgcn_fdot2(__builtin_bit_cast(h2, vn.z), hp[2], an, false);
            ar = __builtin_amdgcn_fdot2(__builtin_bit_cast(h2, vr.w), hp[3], ar, false);
            az = __builtin_amdgcn_fdot2(__builtin_bit_cast(h2, vz.w), hp[3], az, false);
            an = __builtin_amdgcn_fdot2(__builtin_bit_cast(h2, vn.w), hp[3], an, false);
        }
        // sum the 4 k-quarters (aligned 4-groups; all 4 lanes end with the full sum)
        ar += __shfl_xor(ar, 1); ar += __shfl_xor(ar, 2);
        az += __shfl_xor(az, 1); az += __shfl_xor(az, 2);
        an += __shfl_xor(an, 1); an += __shfl_xor(an, 2);

        // gather this step's x_proj values from the role lanes
        float xr = __shfl(pipe0, lbase + 1);
        float xz = __shfl(pipe0, lbase + 2);
        float xn = __shfl(pipe0, lbase + 3);

        // all lanes compute gates (uniform within 4-group; avoids divergence)
        float rg = 1.f / (1.f + __expf(-(xr + ar)));        // b_hh(r) folded into xr
        float zg = 1.f / (1.f + __expf(-(xz + az)));        // b_hh(z) folded into xz
        float narg = xn + rg * (an + bn);
        float aa = fabsf(narg);
        float e = __expf(-2.f * aa);
        float ng = copysignf((1.f - e) / (1.f + e), narg);
        float hnew = (1.f - zg) * ng + zg * hprev;
        hprev = hnew;

        const int nxt = cur ^ 1;
        if (kq == 0) {
            hh[nxt][j >> 6][j & 63] = (_Float16)hnew;
            size_t oi = ((size_t)b * 2048 + t) * 256 + j;
            if constexpr (OUTF32) o32[oi] = hnew; else o16[oi] = (_Float16)hnew;
        }
        __syncthreads();
        cur = nxt;
        pipe0 = pipe1; pipe1 = pnew;
    }
}

// Variant A (layer 1): pin occupancy via waves_per_eu(4,4) -> budget 128 VGPR
__global__
__attribute__((amdgpu_flat_work_group_size(1024, 1024), amdgpu_waves_per_eu(4, 4)))
void gru_scan_wpe(const float* __restrict__ xp, const _Float16* __restrict__ Whh,
                  const float* __restrict__ bhh, float* __restrict__ o32,
                  _Float16* __restrict__ o16) {
    gru_scan_body<false>(xp, Whh, bhh, o32, o16);
}

// Variant B (layer 2): pin the VGPR cap directly
__global__
__attribute__((amdgpu_flat_work_group_size(1024, 1024), amdgpu_num_vgpr(128)))
void gru_scan_nvg(const float* __restrict__ xp, const _Float16* __restrict__ Whh,
                  const float* __restrict__ bhh, float* __restrict__ o32,
                  _Float16* __restrict__ o16) {
    gru_scan_body<true>(xp, Whh, bhh, o32, o16);
}

// ---------------- launch ----------------
extern "C" void kernel_launch(void* const* d_in, const int* in_sizes, int n_in,
                              void* d_out, int out_size, void* d_ws, size_t ws_size,
                              hipStream_t stream) {
    const float* x    = (const float*)d_in[0];
    const float* W_ih = (const float*)d_in[1];
    const float* W_hh = (const float*)d_in[2];
    const float* b_ih = (const float*)d_in[3];
    const float* b_hh = (const float*)d_in[4];
    float* out = (float*)d_out;

    char* ws = (char*)d_ws;
    float*     xproj = (float*)ws;                                   // 201,326,592 B
    _Float16*  Wih_h = (_Float16*)(ws + 201326592);
    _Float16*  Whh_h = (_Float16*)(ws + 201326592 + 786432);
    _Float16*  y1h   = (_Float16*)(ws + 201326592 + 2 * 786432);     // 33,554,432 B
    float*     bias2 = (float*)(ws + 201326592 + 2 * 786432 + 33554432);  // 6,144 B

    cvt_f32_f16<<<1536, 256, 0, stream>>>(W_ih, Wih_h, 393216);
    cvt_f32_f16<<<1536, 256, 0, stream>>>(W_hh, Whh_h, 393216);
    prep_bias<<<6, 256, 0, stream>>>(b_ih, b_hh, bias2, 1536);

    gemm_xproj<false><<<dim3(512, 6), 256, 0, stream>>>(x, Wih_h, bias2, xproj);
    gru_scan_wpe<<<32, 1024, 0, stream>>>(xproj, Whh_h, b_hh, nullptr, y1h);

    gemm_xproj<true><<<dim3(512, 6), 256, 0, stream>>>(y1h, Wih_h + 196608, bias2 + 768, xproj);
    gru_scan_nvg<<<32, 1024, 0, stream>>>(xproj, Whh_h + 196608, b_hh + 768, out, nullptr);
}